// Round 9
// baseline (361.976 us; speedup 1.0000x reference)
//
#include <hip/hip_runtime.h>
#include <hip/hip_bf16.h>

// ---------------- problem constants ----------------
#define N_NODES 10000
#define E_REAL  80000
#define E_TOTAL 90000
#define IN_DIM  768
#define HID     512
#define HEADS   4
#define OUT_DIM 768
#define HD1     (HEADS * HID)   // 2048
#define NEG_SLOPE 0.2f
#define H1_HSTRIDE (N_NODES * HID)   // head-major h1b: [4][10000][512]

typedef unsigned short ushort_t;
typedef unsigned int uint_t;

// ---------------- bf16 helpers ----------------
__device__ inline float b2f(ushort_t u) { return __uint_as_float(((uint_t)u) << 16); }
__device__ inline ushort_t f2b(float f) {
    __hip_bfloat16 h = __float2bfloat16(f);   // RNE
    return *reinterpret_cast<ushort_t*>(&h);
}

__device__ inline void edge_sd(const int* __restrict__ ei, int e, int& s, int& d) {
    if (e < E_REAL) { s = ei[e]; d = ei[E_REAL + e]; }
    else            { s = e - E_REAL; d = s; }   // self-loop
}

// async global->LDS, 16 B per lane; LDS dest = uniform base + lane*16
#define GLDS(g, l) __builtin_amdgcn_global_load_lds( \
    (const __attribute__((address_space(1))) void*)(g), \
    (__attribute__((address_space(3))) void*)(l), 16, 0, 0)

// ---------------- workspace layout (bytes) ----------------
static const long B_H1B  = 0L;           // h1b bf16 (head-major): 40,960,000
static const long B_HB   = 40960000L;    // hb  bf16 (row-major):  40,960,000
static const long B_XB   = 81920000L;    // xb / h2b bf16: 15,360,000
static const long B_W1T  = 97280000L;    // W1^T bf16
static const long B_W2T  = 100425728L;   // W2^T bf16
static const long B_SM   = 103571456L;
// small-buffer offsets (floats/ints, relative to sm)
// [0..110000) floats are zeroed each call (as1, ad1, as2, ad2, cnt)
static const long SM_AS1   = 0;         // 40000
static const long SM_AD1   = 40000;     // 40000
static const long SM_AS2   = 80000;     // 10000
static const long SM_AD2   = 90000;     // 10000
static const long SM_CNT   = 100000;    // 10000 ints (zeroed each call)
static const long SM_ROWS  = 110000;    // 10001 ints
static const long SM_CURS  = 120016;    // 10000 ints
static const long SM_END   = 130016;
static const long B_CSRS = B_SM + SM_END * 4;   // 90000 ints (src)

// ---------------- cast fp32 -> bf16 (row-major, 8/thread) ----------------
__global__ __launch_bounds__(256)
void cast_bf16(const float* __restrict__ in, ushort_t* __restrict__ o, long n) {
    long i = ((long)blockIdx.x * 256 + threadIdx.x) * 8;
    if (i >= n) return;
    float4 v0 = *(const float4*)(in + i);
    float4 v1 = *(const float4*)(in + i + 4);
    ushort_t r[8] = {f2b(v0.x), f2b(v0.y), f2b(v0.z), f2b(v0.w),
                     f2b(v1.x), f2b(v1.y), f2b(v1.z), f2b(v1.w)};
    *(uint4*)(o + i) = *(uint4*)r;
}

// ---------------- cast + transpose: W[K][N] fp32 -> WT[N][K] bf16 ----------
__global__ __launch_bounds__(256)
void cast_transpose(const float* __restrict__ W, ushort_t* __restrict__ WT,
                    int K, int N) {
    __shared__ ushort_t t[32][33];
    const int n0 = blockIdx.x * 32, k0 = blockIdx.y * 32;
    const int tx = threadIdx.x & 31, ty = threadIdx.x >> 5;
#pragma unroll
    for (int i = 0; i < 4; ++i) {
        int k = ty + i * 8;
        t[k][tx] = f2b(W[(long)(k0 + k) * N + n0 + tx]);
    }
    __syncthreads();
#pragma unroll
    for (int i = 0; i < 4; ++i) {
        int n = ty + i * 8;
        WT[(long)(n0 + n) * K + k0 + tx] = t[tx][n];
    }
}

// ---------------- bf16 MFMA GEMM, 8-phase-style pipelined -----------------
// Tile 256x128, BK=64, 512 threads. Triple-buffered LDS, counted vmcnt(6),
// setprio around MFMA. 1D grid, XCD-chunked swizzle (proven -8.5 us R7).
// NEW (R9): fused attention-dot epilogue — per-row ps/pd partials computed
// from acc registers (a_s index == output col), 16-lane shfl_xor reduce
// (quads hold distinct rows), atomicAdd into Os/Od. Replaces the attn1 /
// attn2 kernels (saves 40+15 MB of h re-reads + 2 dispatches).
typedef short bf16x8 __attribute__((ext_vector_type(8)));
typedef float f32x4 __attribute__((ext_vector_type(4)));

#define GBM 256
#define GBN 128
#define GBK 64
#define ABUF (GBM * GBK)        // 16384 elements per A buffer
#define BBUF (GBN * GBK)        // 8192 elements per B buffer
#define GEMM_LDS_BYTES ((3 * (ABUF + BBUF)) * 2)   // 147456 B

template<int CMODE>
__global__ __launch_bounds__(512)
void gemm8p(const ushort_t* __restrict__ A, const ushort_t* __restrict__ BT,
            ushort_t* __restrict__ C, const float* __restrict__ As_,
            const float* __restrict__ Ad_, float* __restrict__ Os_,
            float* __restrict__ Od_, int M, int N, int K, int gx, int rpx) {
    extern __shared__ ushort_t sm_[];
    ushort_t* smA = sm_;                 // 3 * ABUF
    ushort_t* smB = sm_ + 3 * ABUF;      // 3 * BBUF
    const int tid  = threadIdx.x;
    const int wave = tid >> 6, lane = tid & 63;
    const int quad = lane >> 4, l16 = lane & 15;
    // XCD-chunked block remap (1D grid)
    const int id  = blockIdx.x;
    const int xcd = id & 7, r = id >> 3;
    const int bm = (xcd * rpx + r / gx) * GBM;
    const int bn = (r % gx) * GBN;
    const int wr = (wave >> 1) * 64, wc = (wave & 1) * 64;
    const int NT = K / GBK;

    const int  rA  = tid >> 3;                                   // 0..63
    const long cs8 = (long)(((tid & 7) ^ ((tid >> 3) & 7)) * 8); // elem offset
    const ushort_t* aSrc = A  + (long)(bm + rA) * K + cs8;
    const ushort_t* bSrc = BT + (long)(bn + rA) * K + cs8;

    const int aRd  = (wr + l16) * GBK;
    const int bRd  = (wc + l16) * GBK;
    const int swz8 = l16 & 7;
    const int chq0 = ((quad)     ^ swz8) * 8;   // kk=0 half
    const int chq1 = ((4 + quad) ^ swz8) * 8;   // kk=1 half

    f32x4 acc[4][4] = {};

    // ---- prologue: stage tiles 0 and 1 ----
#pragma unroll
    for (int tt = 0; tt < 2; ++tt) {
        const long kt = (long)tt * GBK;
#pragma unroll
        for (int i = 0; i < 4; ++i)
            GLDS(aSrc + (long)i * 64 * K + kt,
                 smA + tt * ABUF + (i * 512 + wave * 64) * 8);
#pragma unroll
        for (int i = 0; i < 2; ++i)
            GLDS(bSrc + (long)i * 64 * K + kt,
                 smB + tt * BBUF + (i * 512 + wave * 64) * 8);
    }
    asm volatile("s_waitcnt vmcnt(6)" ::: "memory");   // tile 0 resident
    __builtin_amdgcn_s_barrier();
    __builtin_amdgcn_sched_barrier(0);

    int bc = 0, bnx = 1, bs = 2;   // compute / next / stage buffers
    for (int t = 0; t < NT; ++t) {
        const int offA = bc * ABUF, offB = bc * BBUF;
        const bool stage = (t + 2 < NT);
        const long kt2 = (long)(t + 2) * GBK;
        bf16x8 bfr[2][4], af[2][2];

        // ---------- phase 1: B full + A rows wr..wr+31 ----------
#pragma unroll
        for (int j = 0; j < 4; ++j) {
            bfr[0][j] = *(const bf16x8*)(smB + offB + bRd + j * 1024 + chq0);
            bfr[1][j] = *(const bf16x8*)(smB + offB + bRd + j * 1024 + chq1);
        }
#pragma unroll
        for (int ii = 0; ii < 2; ++ii) {
            af[0][ii] = *(const bf16x8*)(smA + offA + aRd + ii * 1024 + chq0);
            af[1][ii] = *(const bf16x8*)(smA + offA + aRd + ii * 1024 + chq1);
        }
        if (stage) {
            GLDS(aSrc + kt2,                    smA + bs * ABUF + (wave * 64) * 8);
            GLDS(aSrc + (long)1 * 64 * K + kt2, smA + bs * ABUF + (512 + wave * 64) * 8);
            GLDS(aSrc + (long)2 * 64 * K + kt2, smA + bs * ABUF + (1024 + wave * 64) * 8);
        }
        __builtin_amdgcn_sched_barrier(0);
        __builtin_amdgcn_s_barrier();
        __builtin_amdgcn_sched_barrier(0);
        __builtin_amdgcn_s_setprio(1);
#pragma unroll
        for (int kk = 0; kk < 2; ++kk)
#pragma unroll
            for (int ii = 0; ii < 2; ++ii)
#pragma unroll
                for (int j = 0; j < 4; ++j)
                    acc[ii][j] = __builtin_amdgcn_mfma_f32_16x16x32_bf16(
                        af[kk][ii], bfr[kk][j], acc[ii][j], 0, 0, 0);
        __builtin_amdgcn_s_setprio(0);
        __builtin_amdgcn_sched_barrier(0);
        __builtin_amdgcn_s_barrier();
        __builtin_amdgcn_sched_barrier(0);

        // ---------- phase 2: A rows wr+32..wr+63 ----------
#pragma unroll
        for (int ii = 0; ii < 2; ++ii) {
            af[0][ii] = *(const bf16x8*)(smA + offA + aRd + (2 + ii) * 1024 + chq0);
            af[1][ii] = *(const bf16x8*)(smA + offA + aRd + (2 + ii) * 1024 + chq1);
        }
        if (stage) {
            GLDS(aSrc + (long)3 * 64 * K + kt2, smA + bs * ABUF + (1536 + wave * 64) * 8);
            GLDS(bSrc + kt2,                    smB + bs * BBUF + (wave * 64) * 8);
            GLDS(bSrc + (long)1 * 64 * K + kt2, smB + bs * BBUF + (512 + wave * 64) * 8);
        }
        if (stage)             { asm volatile("s_waitcnt vmcnt(6)" ::: "memory"); }
        else if (t + 1 < NT)   { asm volatile("s_waitcnt vmcnt(0)" ::: "memory"); }
        __builtin_amdgcn_sched_barrier(0);
        __builtin_amdgcn_s_barrier();
        __builtin_amdgcn_sched_barrier(0);
        __builtin_amdgcn_s_setprio(1);
#pragma unroll
        for (int kk = 0; kk < 2; ++kk)
#pragma unroll
            for (int ii = 0; ii < 2; ++ii)
#pragma unroll
                for (int j = 0; j < 4; ++j)
                    acc[2 + ii][j] = __builtin_amdgcn_mfma_f32_16x16x32_bf16(
                        af[kk][ii], bfr[kk][j], acc[2 + ii][j], 0, 0, 0);
        __builtin_amdgcn_s_setprio(0);
        __builtin_amdgcn_sched_barrier(0);
        __builtin_amdgcn_s_barrier();
        __builtin_amdgcn_sched_barrier(0);

        int tmp = bc; bc = bnx; bnx = bs; bs = tmp;
    }

    // ------- epilogue: C write + fused attention-dot partials -------
    // a_s/a_d index == output col (a1_src flattens to [HEADS*HID]).
    float asv[4], adv4[4];
#pragma unroll
    for (int j = 0; j < 4; ++j) {
        int c = bn + wc + j * 16 + l16;
        asv[j]  = As_[c];
        adv4[j] = Ad_[c];
    }
#pragma unroll
    for (int i = 0; i < 4; ++i) {
#pragma unroll
        for (int r2 = 0; r2 < 4; ++r2) {
            int row = bm + wr + i * 16 + quad * 4 + r2;
            if (row >= M) continue;
            float ps = 0.f, pd = 0.f;
#pragma unroll
            for (int j = 0; j < 4; ++j) {
                int col = bn + wc + j * 16 + l16;
                float av = acc[i][j][r2];
                ps += av * asv[j];
                pd += av * adv4[j];
                if (CMODE == 0) {
                    C[(long)row * N + col] = f2b(av);
                } else {
                    // head-major: head = col>>9
                    C[(long)(col >> 9) * H1_HSTRIDE + (long)row * HID + (col & 511)]
                        = f2b(av);
                }
            }
            // reduce across the 16-lane group (quads = distinct rows)
#pragma unroll
            for (int off = 1; off < 16; off <<= 1) {
                ps += __shfl_xor(ps, off);
                pd += __shfl_xor(pd, off);
            }
            if (l16 == 0) {
                int oi = (CMODE == 1) ? (row * HEADS + (bn >> 9)) : row;
                atomicAdd(&Os_[oi], ps);
                atomicAdd(&Od_[oi], pd);
            }
        }
    }
}

// ---------------- CSR build ----------------
__global__ __launch_bounds__(256)
void hist_dst(const int* __restrict__ ei, int* __restrict__ cnt) {
    int e = blockIdx.x * 256 + threadIdx.x;
    if (e >= E_TOTAL) return;
    int s, d; edge_sd(ei, e, s, d);
    atomicAdd(&cnt[d], 1);
}

#define SCAN_CH 40
__global__ __launch_bounds__(256)
void scan_nodes(const int* __restrict__ cnt, int* __restrict__ rows,
                int* __restrict__ curs) {
    __shared__ int part[256];
    const int tid = threadIdx.x;
    const int base = tid * SCAN_CH;
    int local[SCAN_CH];
    int sum = 0;
#pragma unroll
    for (int i = 0; i < SCAN_CH; ++i) {
        int idx = base + i;
        int v = (idx < N_NODES) ? cnt[idx] : 0;
        local[i] = v; sum += v;
    }
    part[tid] = sum;
    __syncthreads();
    for (int off = 1; off < 256; off <<= 1) {
        int v = (tid >= off) ? part[tid - off] : 0;
        __syncthreads();
        part[tid] += v;
        __syncthreads();
    }
    int run = part[tid] - sum;   // exclusive prefix
#pragma unroll
    for (int i = 0; i < SCAN_CH; ++i) {
        int idx = base + i;
        if (idx < N_NODES) { rows[idx] = run; curs[idx] = run; run += local[i]; }
    }
    if (tid == 255) rows[N_NODES] = run;
}

__global__ __launch_bounds__(256)
void scatter_edges(const int* __restrict__ ei, int* __restrict__ curs,
                   int* __restrict__ csr_src) {
    int e = blockIdx.x * 256 + threadIdx.x;
    if (e >= E_TOTAL) return;
    int s, d; edge_sd(ei, e, s, d);
    int pos = atomicAdd(&curs[d], 1);
    csr_src[pos] = s;
}

// ---------------- layer-1 aggregate + fused softmax + bias + ELU ---------
// R4's measured-best form: one wave per (node, head), 40000 blocks.
// blockIdx%8 maps head h to XCD residues {2h,2h+1} (working-set pinning).
// Per-edge full-wave uint4 gather (1 KB/instr), PF4.
__global__ __launch_bounds__(64)
void agg1(const int* __restrict__ rows, const int* __restrict__ csr_src,
          const float* __restrict__ as_n, const float* __restrict__ ad_n,
          const ushort_t* __restrict__ hf, const float* __restrict__ b1,
          ushort_t* __restrict__ o) {
    const int id = blockIdx.x;
    const int g = id & 7, j = id >> 3;
    const int hh = g >> 1;
    const int n = j * 2 + (g & 1);
    const int lane = threadIdx.x;
    const int beg = rows[n], end = rows[n + 1];
    const ushort_t* hsl = hf + (long)hh * H1_HSTRIDE;
    const float adv = ad_n[(long)n * HEADS + hh];
    float acc[8] = {};
    float dsum = 0.f;
    for (int k = beg; k < end; k += 4) {
        int nk = end - k; if (nk > 4) nk = 4;
        uint4 v[4]; float ex[4];
#pragma unroll
        for (int u = 0; u < 4; ++u) {
            if (u < nk) {
                int s = csr_src[k + u];
                float sc = as_n[(long)s * HEADS + hh] + adv;
                sc = sc > 0.f ? sc : NEG_SLOPE * sc;
                ex[u] = __expf(sc);
                v[u]  = *(const uint4*)(hsl + (long)s * HID + lane * 8);
            }
        }
#pragma unroll
        for (int u = 0; u < 4; ++u) {
            if (u < nk) {
                dsum += ex[u];
                const ushort_t* p = (const ushort_t*)&v[u];
#pragma unroll
                for (int c = 0; c < 8; ++c) acc[c] += ex[u] * b2f(p[c]);
            }
        }
    }
    const float dinv = 1.f / (dsum + 1e-16f);
    const float* bp = b1 + hh * HID + lane * 8;
    ushort_t r[8];
#pragma unroll
    for (int c = 0; c < 8; ++c) {
        float vv = acc[c] * dinv + bp[c];
        r[c] = f2b(vv > 0.f ? vv : expm1f(vv));
    }
    *(uint4*)(o + (long)n * HD1 + hh * HID + lane * 8) = *(uint4*)r;
}

// ---------------- layer-2 aggregate + fused softmax + bias -> fp32 -------
// 4 nodes per 256-thread block (wave = node); unroll depth 8.
#define PF2 8
__global__ __launch_bounds__(256)
void agg2(const int* __restrict__ rows, const int* __restrict__ csr_src,
          const float* __restrict__ as_n, const float* __restrict__ ad_n,
          const ushort_t* __restrict__ hf, const float* __restrict__ b2,
          float* __restrict__ out) {
    const int n = blockIdx.x * 4 + (threadIdx.x >> 6);
    const int lane = threadIdx.x & 63;
    const int beg = rows[n], end = rows[n + 1];
    const float adv = ad_n[n];
    float acc[12] = {};
    float dsum = 0.f;
    for (int k = beg; k < end; k += PF2) {
        int nk = end - k; if (nk > PF2) nk = PF2;
        int sv[PF2];
#pragma unroll
        for (int u = 0; u < PF2; ++u)
            if (u < nk) sv[u] = csr_src[k + u];
        uint4 v4[PF2]; uint2 v2[PF2]; float ex[PF2];
#pragma unroll
        for (int u = 0; u < PF2; ++u) {
            if (u < nk) {
                float sc = as_n[sv[u]] + adv;
                sc = sc > 0.f ? sc : NEG_SLOPE * sc;
                ex[u] = __expf(sc);
                const ushort_t* hp = hf + (long)sv[u] * OUT_DIM;
                v4[u] = *(const uint4*)(hp + lane * 8);
                v2[u] = *(const uint2*)(hp + 512 + lane * 4);
            }
        }
#pragma unroll
        for (int u = 0; u < PF2; ++u) {
            if (u < nk) {
                dsum += ex[u];
                const ushort_t* p4 = (const ushort_t*)&v4[u];
                const ushort_t* p2 = (const ushort_t*)&v2[u];
#pragma unroll
                for (int c = 0; c < 8; ++c) acc[c] += ex[u] * b2f(p4[c]);
#pragma unroll
                for (int c = 0; c < 4; ++c) acc[8 + c] += ex[u] * b2f(p2[c]);
            }
        }
    }
    const float dinv = 1.f / (dsum + 1e-16f);
    float* op = out + (long)n * OUT_DIM;
#pragma unroll
    for (int c = 0; c < 8; ++c)
        op[lane * 8 + c] = acc[c] * dinv + b2[lane * 8 + c];
#pragma unroll
    for (int c = 0; c < 4; ++c)
        op[512 + lane * 4 + c] = acc[8 + c] * dinv + b2[512 + lane * 4 + c];
}

extern "C" void kernel_launch(void* const* d_in, const int* in_sizes, int n_in,
                              void* d_out, int out_size, void* d_ws, size_t ws_size,
                              hipStream_t stream) {
    const float* x   = (const float*)d_in[0];
    const int*   ei  = (const int*)d_in[1];
    const float* W1  = (const float*)d_in[2];
    const float* a1s = (const float*)d_in[3];
    const float* a1d = (const float*)d_in[4];
    const float* b1  = (const float*)d_in[5];
    const float* W2  = (const float*)d_in[6];
    const float* a2s = (const float*)d_in[7];
    const float* a2d = (const float*)d_in[8];
    const float* b2  = (const float*)d_in[9];
    float* out = (float*)d_out;
    char* base = (char*)d_ws;

    ushort_t* h1b = (ushort_t*)(base + B_H1B);   // head-major [4][10000][512]
    ushort_t* hb  = (ushort_t*)(base + B_HB);    // row-major  [10000][2048]
    ushort_t* xb  = (ushort_t*)(base + B_XB);
    ushort_t* h2b = xb;
    ushort_t* w1t = (ushort_t*)(base + B_W1T);
    ushort_t* w2t = (ushort_t*)(base + B_W2T);
    float*    sm  = (float*)(base + B_SM);

    float* as1  = sm + SM_AS1;
    float* ad1  = sm + SM_AD1;
    float* as2  = sm + SM_AS2;
    float* ad2  = sm + SM_AD2;
    int* cnt    = (int*)(sm + SM_CNT);
    int* rows   = (int*)(sm + SM_ROWS);
    int* curs   = (int*)(sm + SM_CURS);
    int* csr_src = (int*)(base + B_CSRS);

    // zero as1/ad1/as2/ad2 (atomic targets) + degree histogram: floats [0,110000)
    hipMemsetAsync(sm, 0, 110000 * sizeof(float), stream);

    // ---------------- casts + CSR build ----------------
    {
        long nx = (long)N_NODES * IN_DIM;
        cast_bf16<<<(int)(nx / 8 / 256 + 1), 256, 0, stream>>>(x, xb, nx);
        cast_transpose<<<dim3(HD1 / 32, IN_DIM / 32), 256, 0, stream>>>(W1, w1t, IN_DIM, HD1);
        cast_transpose<<<dim3(OUT_DIM / 32, HD1 / 32), 256, 0, stream>>>(W2, w2t, HD1, OUT_DIM);
        hist_dst<<<(E_TOTAL + 255) / 256, 256, 0, stream>>>(ei, cnt);
        scan_nodes<<<1, 256, 0, stream>>>(cnt, rows, curs);
        scatter_edges<<<(E_TOTAL + 255) / 256, 256, 0, stream>>>(ei, curs, csr_src);
    }

    // grid geometry: 40 row-blocks, 8 XCDs -> rpx=5 row-panels per XCD
    // gemm1: gx=16 (2048/128), nb=640; gemm2: gx=6 (768/128), nb=240
    // ---------------- layer 1: GATConv(768 -> 512, heads=4, concat) --------
    gemm8p<1><<<640, 512, GEMM_LDS_BYTES, stream>>>(
        xb, w1t, h1b, a1s, a1d, as1, ad1, N_NODES, HD1, IN_DIM, 16, 5);
    agg1<<<N_NODES * HEADS, 64, 0, stream>>>(
        rows, csr_src, as1, ad1, h1b, b1, hb);

    // ---------------- layer 2: GATConv(2048 -> 768, heads=1, mean) ---------
    gemm8p<0><<<240, 512, GEMM_LDS_BYTES, stream>>>(
        hb, w2t, h2b, a2s, a2d, as2, ad2, N_NODES, OUT_DIM, HD1, 6, 5);
    agg2<<<N_NODES / 4, 256, 0, stream>>>(
        rows, csr_src, as2, ad2, h2b, b2, out);
}

// Round 10
// 324.912 us; speedup vs baseline: 1.1141x; 1.1141x over previous
//
#include <hip/hip_runtime.h>
#include <hip/hip_bf16.h>

// ---------------- problem constants ----------------
#define N_NODES 10000
#define E_REAL  80000
#define E_TOTAL 90000
#define IN_DIM  768
#define HID     512
#define HEADS   4
#define OUT_DIM 768
#define HD1     (HEADS * HID)   // 2048
#define NEG_SLOPE 0.2f
#define H1_HSTRIDE (N_NODES * HID)   // head-major h1b: [4][10000][512]

typedef unsigned short ushort_t;
typedef unsigned int uint_t;

// ---------------- bf16 helpers ----------------
__device__ inline float b2f(ushort_t u) { return __uint_as_float(((uint_t)u) << 16); }
__device__ inline ushort_t f2b(float f) {
    __hip_bfloat16 h = __float2bfloat16(f);   // RNE
    return *reinterpret_cast<ushort_t*>(&h);
}

__device__ inline void edge_sd(const int* __restrict__ ei, int e, int& s, int& d) {
    if (e < E_REAL) { s = ei[e]; d = ei[E_REAL + e]; }
    else            { s = e - E_REAL; d = s; }   // self-loop
}

// async global->LDS, 16 B per lane; LDS dest = uniform base + lane*16
#define GLDS(g, l) __builtin_amdgcn_global_load_lds( \
    (const __attribute__((address_space(1))) void*)(g), \
    (__attribute__((address_space(3))) void*)(l), 16, 0, 0)

// ---------------- workspace layout (bytes) ----------------
static const long B_H1B  = 0L;           // h1b bf16 (head-major): 40,960,000
static const long B_HB   = 40960000L;    // hb  bf16 (row-major):  40,960,000
static const long B_XB   = 81920000L;    // xb / h2b bf16: 15,360,000
static const long B_W1T  = 97280000L;    // W1^T bf16
static const long B_W2T  = 100425728L;   // W2^T bf16
static const long B_SM   = 103571456L;
// small-buffer offsets (floats/ints, relative to sm)
static const long SM_AS1   = 0;         // 40000
static const long SM_AD1   = 40000;     // 40000
static const long SM_AS2   = 80000;     // 10000
static const long SM_AD2   = 90000;     // 10000
static const long SM_CNT   = 100000;    // 10000 ints (zeroed each call)
static const long SM_ROWS  = 110000;    // 10001 ints
static const long SM_CURS  = 120016;    // 10000 ints
static const long SM_END   = 130016;
static const long B_CSRS = B_SM + SM_END * 4;     // 90000 ints (src)
// attention-dot partial buffers (contention-free fused epilogue)
static const long B_PS1 = B_CSRS + 360000L;       // [40000][8] f32 = 1,280,000
static const long B_PD1 = B_PS1 + 1280000L;       // [40000][8] f32
static const long B_PS2 = B_PD1 + 1280000L;       // [10000][12] f32 = 480,000
static const long B_PD2 = B_PS2 + 480000L;        // [10000][12] f32

// ---------------- cast fp32 -> bf16 (row-major, 8/thread) ----------------
__global__ __launch_bounds__(256)
void cast_bf16(const float* __restrict__ in, ushort_t* __restrict__ o, long n) {
    long i = ((long)blockIdx.x * 256 + threadIdx.x) * 8;
    if (i >= n) return;
    float4 v0 = *(const float4*)(in + i);
    float4 v1 = *(const float4*)(in + i + 4);
    ushort_t r[8] = {f2b(v0.x), f2b(v0.y), f2b(v0.z), f2b(v0.w),
                     f2b(v1.x), f2b(v1.y), f2b(v1.z), f2b(v1.w)};
    *(uint4*)(o + i) = *(uint4*)r;
}

// ---------------- cast + transpose: W[K][N] fp32 -> WT[N][K] bf16 ----------
__global__ __launch_bounds__(256)
void cast_transpose(const float* __restrict__ W, ushort_t* __restrict__ WT,
                    int K, int N) {
    __shared__ ushort_t t[32][33];
    const int n0 = blockIdx.x * 32, k0 = blockIdx.y * 32;
    const int tx = threadIdx.x & 31, ty = threadIdx.x >> 5;
#pragma unroll
    for (int i = 0; i < 4; ++i) {
        int k = ty + i * 8;
        t[k][tx] = f2b(W[(long)(k0 + k) * N + n0 + tx]);
    }
    __syncthreads();
#pragma unroll
    for (int i = 0; i < 4; ++i) {
        int n = ty + i * 8;
        WT[(long)(n0 + n) * K + k0 + tx] = t[tx][n];
    }
}

// ---------------- bf16 MFMA GEMM, 8-phase-style pipelined -----------------
// Tile 256x128, BK=64, 512 threads. Triple-buffered LDS, counted vmcnt(6),
// setprio around MFMA. 1D grid, XCD-chunked swizzle.
// Fused attention-dot epilogue v2 (R10): per-row ps/pd partials from acc
// registers, 16-lane shfl_xor reduce, then PLAIN STORE into a per-
// (bn-block, wc-half) partial slot — no atomics (R9's 655K same-line
// atomicAdds serialized at L2 and doubled gemm1's duration). A tiny
// finalize kernel sums the 8 (or 12) slots per entry.
typedef short bf16x8 __attribute__((ext_vector_type(8)));
typedef float f32x4 __attribute__((ext_vector_type(4)));

#define GBM 256
#define GBN 128
#define GBK 64
#define ABUF (GBM * GBK)        // 16384 elements per A buffer
#define BBUF (GBN * GBK)        // 8192 elements per B buffer
#define GEMM_LDS_BYTES ((3 * (ABUF + BBUF)) * 2)   // 147456 B

template<int CMODE>
__global__ __launch_bounds__(512)
void gemm8p(const ushort_t* __restrict__ A, const ushort_t* __restrict__ BT,
            ushort_t* __restrict__ C, const float* __restrict__ As_,
            const float* __restrict__ Ad_, float* __restrict__ Ps_,
            float* __restrict__ Pd_, int M, int N, int K, int gx, int rpx) {
    extern __shared__ ushort_t sm_[];
    ushort_t* smA = sm_;                 // 3 * ABUF
    ushort_t* smB = sm_ + 3 * ABUF;      // 3 * BBUF
    const int tid  = threadIdx.x;
    const int wave = tid >> 6, lane = tid & 63;
    const int quad = lane >> 4, l16 = lane & 15;
    // XCD-chunked block remap (1D grid)
    const int id  = blockIdx.x;
    const int xcd = id & 7, r = id >> 3;
    const int bm = (xcd * rpx + r / gx) * GBM;
    const int bn = (r % gx) * GBN;
    const int wr = (wave >> 1) * 64, wc = (wave & 1) * 64;
    const int NT = K / GBK;

    const int  rA  = tid >> 3;                                   // 0..63
    const long cs8 = (long)(((tid & 7) ^ ((tid >> 3) & 7)) * 8); // elem offset
    const ushort_t* aSrc = A  + (long)(bm + rA) * K + cs8;
    const ushort_t* bSrc = BT + (long)(bn + rA) * K + cs8;

    const int aRd  = (wr + l16) * GBK;
    const int bRd  = (wc + l16) * GBK;
    const int swz8 = l16 & 7;
    const int chq0 = ((quad)     ^ swz8) * 8;   // kk=0 half
    const int chq1 = ((4 + quad) ^ swz8) * 8;   // kk=1 half

    f32x4 acc[4][4] = {};

    // ---- prologue: stage tiles 0 and 1 ----
#pragma unroll
    for (int tt = 0; tt < 2; ++tt) {
        const long kt = (long)tt * GBK;
#pragma unroll
        for (int i = 0; i < 4; ++i)
            GLDS(aSrc + (long)i * 64 * K + kt,
                 smA + tt * ABUF + (i * 512 + wave * 64) * 8);
#pragma unroll
        for (int i = 0; i < 2; ++i)
            GLDS(bSrc + (long)i * 64 * K + kt,
                 smB + tt * BBUF + (i * 512 + wave * 64) * 8);
    }
    asm volatile("s_waitcnt vmcnt(6)" ::: "memory");   // tile 0 resident
    __builtin_amdgcn_s_barrier();
    __builtin_amdgcn_sched_barrier(0);

    int bc = 0, bnx = 1, bs = 2;   // compute / next / stage buffers
    for (int t = 0; t < NT; ++t) {
        const int offA = bc * ABUF, offB = bc * BBUF;
        const bool stage = (t + 2 < NT);
        const long kt2 = (long)(t + 2) * GBK;
        bf16x8 bfr[2][4], af[2][2];

        // ---------- phase 1: B full + A rows wr..wr+31 ----------
#pragma unroll
        for (int j = 0; j < 4; ++j) {
            bfr[0][j] = *(const bf16x8*)(smB + offB + bRd + j * 1024 + chq0);
            bfr[1][j] = *(const bf16x8*)(smB + offB + bRd + j * 1024 + chq1);
        }
#pragma unroll
        for (int ii = 0; ii < 2; ++ii) {
            af[0][ii] = *(const bf16x8*)(smA + offA + aRd + ii * 1024 + chq0);
            af[1][ii] = *(const bf16x8*)(smA + offA + aRd + ii * 1024 + chq1);
        }
        if (stage) {
            GLDS(aSrc + kt2,                    smA + bs * ABUF + (wave * 64) * 8);
            GLDS(aSrc + (long)1 * 64 * K + kt2, smA + bs * ABUF + (512 + wave * 64) * 8);
            GLDS(aSrc + (long)2 * 64 * K + kt2, smA + bs * ABUF + (1024 + wave * 64) * 8);
        }
        __builtin_amdgcn_sched_barrier(0);
        __builtin_amdgcn_s_barrier();
        __builtin_amdgcn_sched_barrier(0);
        __builtin_amdgcn_s_setprio(1);
#pragma unroll
        for (int kk = 0; kk < 2; ++kk)
#pragma unroll
            for (int ii = 0; ii < 2; ++ii)
#pragma unroll
                for (int j = 0; j < 4; ++j)
                    acc[ii][j] = __builtin_amdgcn_mfma_f32_16x16x32_bf16(
                        af[kk][ii], bfr[kk][j], acc[ii][j], 0, 0, 0);
        __builtin_amdgcn_s_setprio(0);
        __builtin_amdgcn_sched_barrier(0);
        __builtin_amdgcn_s_barrier();
        __builtin_amdgcn_sched_barrier(0);

        // ---------- phase 2: A rows wr+32..wr+63 ----------
#pragma unroll
        for (int ii = 0; ii < 2; ++ii) {
            af[0][ii] = *(const bf16x8*)(smA + offA + aRd + (2 + ii) * 1024 + chq0);
            af[1][ii] = *(const bf16x8*)(smA + offA + aRd + (2 + ii) * 1024 + chq1);
        }
        if (stage) {
            GLDS(aSrc + (long)3 * 64 * K + kt2, smA + bs * ABUF + (1536 + wave * 64) * 8);
            GLDS(bSrc + kt2,                    smB + bs * BBUF + (wave * 64) * 8);
            GLDS(bSrc + (long)1 * 64 * K + kt2, smB + bs * BBUF + (512 + wave * 64) * 8);
        }
        if (stage)             { asm volatile("s_waitcnt vmcnt(6)" ::: "memory"); }
        else if (t + 1 < NT)   { asm volatile("s_waitcnt vmcnt(0)" ::: "memory"); }
        __builtin_amdgcn_sched_barrier(0);
        __builtin_amdgcn_s_barrier();
        __builtin_amdgcn_sched_barrier(0);
        __builtin_amdgcn_s_setprio(1);
#pragma unroll
        for (int kk = 0; kk < 2; ++kk)
#pragma unroll
            for (int ii = 0; ii < 2; ++ii)
#pragma unroll
                for (int j = 0; j < 4; ++j)
                    acc[2 + ii][j] = __builtin_amdgcn_mfma_f32_16x16x32_bf16(
                        af[kk][ii], bfr[kk][j], acc[2 + ii][j], 0, 0, 0);
        __builtin_amdgcn_s_setprio(0);
        __builtin_amdgcn_sched_barrier(0);
        __builtin_amdgcn_s_barrier();
        __builtin_amdgcn_sched_barrier(0);

        int tmp = bc; bc = bnx; bnx = bs; bs = tmp;
    }

    // ------- epilogue: C write + fused attention-dot partials (no atomics) --
    float asv[4], adv4[4];
#pragma unroll
    for (int j = 0; j < 4; ++j) {
        int c = bn + wc + j * 16 + l16;
        asv[j]  = As_[c];
        adv4[j] = Ad_[c];
    }
#pragma unroll
    for (int i = 0; i < 4; ++i) {
#pragma unroll
        for (int r2 = 0; r2 < 4; ++r2) {
            int row = bm + wr + i * 16 + quad * 4 + r2;
            if (row >= M) continue;
            float ps = 0.f, pd = 0.f;
#pragma unroll
            for (int j = 0; j < 4; ++j) {
                int col = bn + wc + j * 16 + l16;
                float av = acc[i][j][r2];
                ps += av * asv[j];
                pd += av * adv4[j];
                if (CMODE == 0) {
                    C[(long)row * N + col] = f2b(av);
                } else {
                    // head-major: head = col>>9
                    C[(long)(col >> 9) * H1_HSTRIDE + (long)row * HID + (col & 511)]
                        = f2b(av);
                }
            }
            // reduce across the 16-lane group (quads = distinct rows)
#pragma unroll
            for (int off = 1; off < 16; off <<= 1) {
                ps += __shfl_xor(ps, off);
                pd += __shfl_xor(pd, off);
            }
            if (l16 == 0) {
                if (CMODE == 1) {
                    long ent = (long)row * HEADS + (bn >> 9);
                    int  p   = ((bn >> 7) & 3) * 2 + (wave & 1);  // 0..7
                    Ps_[ent * 8 + p] = ps;
                    Pd_[ent * 8 + p] = pd;
                } else {
                    int p = (bn >> 7) * 2 + (wave & 1);            // 0..11
                    Ps_[(long)row * 12 + p] = ps;
                    Pd_[(long)row * 12 + p] = pd;
                }
            }
        }
    }
}

// ---------------- finalize attention dots: sum partial slots -------------
__global__ __launch_bounds__(256)
void fin1(const float* __restrict__ ps, const float* __restrict__ pd,
          float* __restrict__ os, float* __restrict__ od) {
    int e = blockIdx.x * 256 + threadIdx.x;
    if (e >= N_NODES * HEADS) return;
    float s = 0.f, d = 0.f;
#pragma unroll
    for (int p = 0; p < 8; ++p) { s += ps[(long)e * 8 + p]; d += pd[(long)e * 8 + p]; }
    os[e] = s; od[e] = d;
}

__global__ __launch_bounds__(256)
void fin2(const float* __restrict__ ps, const float* __restrict__ pd,
          float* __restrict__ os, float* __restrict__ od) {
    int e = blockIdx.x * 256 + threadIdx.x;
    if (e >= N_NODES) return;
    float s = 0.f, d = 0.f;
#pragma unroll
    for (int p = 0; p < 12; ++p) { s += ps[(long)e * 12 + p]; d += pd[(long)e * 12 + p]; }
    os[e] = s; od[e] = d;
}

// ---------------- CSR build ----------------
__global__ __launch_bounds__(256)
void hist_dst(const int* __restrict__ ei, int* __restrict__ cnt) {
    int e = blockIdx.x * 256 + threadIdx.x;
    if (e >= E_TOTAL) return;
    int s, d; edge_sd(ei, e, s, d);
    atomicAdd(&cnt[d], 1);
}

#define SCAN_CH 40
__global__ __launch_bounds__(256)
void scan_nodes(const int* __restrict__ cnt, int* __restrict__ rows,
                int* __restrict__ curs) {
    __shared__ int part[256];
    const int tid = threadIdx.x;
    const int base = tid * SCAN_CH;
    int local[SCAN_CH];
    int sum = 0;
#pragma unroll
    for (int i = 0; i < SCAN_CH; ++i) {
        int idx = base + i;
        int v = (idx < N_NODES) ? cnt[idx] : 0;
        local[i] = v; sum += v;
    }
    part[tid] = sum;
    __syncthreads();
    for (int off = 1; off < 256; off <<= 1) {
        int v = (tid >= off) ? part[tid - off] : 0;
        __syncthreads();
        part[tid] += v;
        __syncthreads();
    }
    int run = part[tid] - sum;   // exclusive prefix
#pragma unroll
    for (int i = 0; i < SCAN_CH; ++i) {
        int idx = base + i;
        if (idx < N_NODES) { rows[idx] = run; curs[idx] = run; run += local[i]; }
    }
    if (tid == 255) rows[N_NODES] = run;
}

__global__ __launch_bounds__(256)
void scatter_edges(const int* __restrict__ ei, int* __restrict__ curs,
                   int* __restrict__ csr_src) {
    int e = blockIdx.x * 256 + threadIdx.x;
    if (e >= E_TOTAL) return;
    int s, d; edge_sd(ei, e, s, d);
    int pos = atomicAdd(&curs[d], 1);
    csr_src[pos] = s;
}

// ---------------- layer-1 aggregate + fused softmax + bias + ELU ---------
// R4's measured-best form: one wave per (node, head), 40000 blocks.
// blockIdx%8 maps head h to XCD residues {2h,2h+1} (working-set pinning).
// Per-edge full-wave uint4 gather (1 KB/instr), PF4.
__global__ __launch_bounds__(64)
void agg1(const int* __restrict__ rows, const int* __restrict__ csr_src,
          const float* __restrict__ as_n, const float* __restrict__ ad_n,
          const ushort_t* __restrict__ hf, const float* __restrict__ b1,
          ushort_t* __restrict__ o) {
    const int id = blockIdx.x;
    const int g = id & 7, j = id >> 3;
    const int hh = g >> 1;
    const int n = j * 2 + (g & 1);
    const int lane = threadIdx.x;
    const int beg = rows[n], end = rows[n + 1];
    const ushort_t* hsl = hf + (long)hh * H1_HSTRIDE;
    const float adv = ad_n[(long)n * HEADS + hh];
    float acc[8] = {};
    float dsum = 0.f;
    for (int k = beg; k < end; k += 4) {
        int nk = end - k; if (nk > 4) nk = 4;
        uint4 v[4]; float ex[4];
#pragma unroll
        for (int u = 0; u < 4; ++u) {
            if (u < nk) {
                int s = csr_src[k + u];
                float sc = as_n[(long)s * HEADS + hh] + adv;
                sc = sc > 0.f ? sc : NEG_SLOPE * sc;
                ex[u] = __expf(sc);
                v[u]  = *(const uint4*)(hsl + (long)s * HID + lane * 8);
            }
        }
#pragma unroll
        for (int u = 0; u < 4; ++u) {
            if (u < nk) {
                dsum += ex[u];
                const ushort_t* p = (const ushort_t*)&v[u];
#pragma unroll
                for (int c = 0; c < 8; ++c) acc[c] += ex[u] * b2f(p[c]);
            }
        }
    }
    const float dinv = 1.f / (dsum + 1e-16f);
    const float* bp = b1 + hh * HID + lane * 8;
    ushort_t r[8];
#pragma unroll
    for (int c = 0; c < 8; ++c) {
        float vv = acc[c] * dinv + bp[c];
        r[c] = f2b(vv > 0.f ? vv : expm1f(vv));
    }
    *(uint4*)(o + (long)n * HD1 + hh * HID + lane * 8) = *(uint4*)r;
}

// ---------------- layer-2 aggregate + fused softmax + bias -> fp32 -------
// 4 nodes per 256-thread block (wave = node); unroll depth 8.
#define PF2 8
__global__ __launch_bounds__(256)
void agg2(const int* __restrict__ rows, const int* __restrict__ csr_src,
          const float* __restrict__ as_n, const float* __restrict__ ad_n,
          const ushort_t* __restrict__ hf, const float* __restrict__ b2,
          float* __restrict__ out) {
    const int n = blockIdx.x * 4 + (threadIdx.x >> 6);
    const int lane = threadIdx.x & 63;
    const int beg = rows[n], end = rows[n + 1];
    const float adv = ad_n[n];
    float acc[12] = {};
    float dsum = 0.f;
    for (int k = beg; k < end; k += PF2) {
        int nk = end - k; if (nk > PF2) nk = PF2;
        int sv[PF2];
#pragma unroll
        for (int u = 0; u < PF2; ++u)
            if (u < nk) sv[u] = csr_src[k + u];
        uint4 v4[PF2]; uint2 v2[PF2]; float ex[PF2];
#pragma unroll
        for (int u = 0; u < PF2; ++u) {
            if (u < nk) {
                float sc = as_n[sv[u]] + adv;
                sc = sc > 0.f ? sc : NEG_SLOPE * sc;
                ex[u] = __expf(sc);
                const ushort_t* hp = hf + (long)sv[u] * OUT_DIM;
                v4[u] = *(const uint4*)(hp + lane * 8);
                v2[u] = *(const uint2*)(hp + 512 + lane * 4);
            }
        }
#pragma unroll
        for (int u = 0; u < PF2; ++u) {
            if (u < nk) {
                dsum += ex[u];
                const ushort_t* p4 = (const ushort_t*)&v4[u];
                const ushort_t* p2 = (const ushort_t*)&v2[u];
#pragma unroll
                for (int c = 0; c < 8; ++c) acc[c] += ex[u] * b2f(p4[c]);
#pragma unroll
                for (int c = 0; c < 4; ++c) acc[8 + c] += ex[u] * b2f(p2[c]);
            }
        }
    }
    const float dinv = 1.f / (dsum + 1e-16f);
    float* op = out + (long)n * OUT_DIM;
#pragma unroll
    for (int c = 0; c < 8; ++c)
        op[lane * 8 + c] = acc[c] * dinv + b2[lane * 8 + c];
#pragma unroll
    for (int c = 0; c < 4; ++c)
        op[512 + lane * 4 + c] = acc[8 + c] * dinv + b2[512 + lane * 4 + c];
}

extern "C" void kernel_launch(void* const* d_in, const int* in_sizes, int n_in,
                              void* d_out, int out_size, void* d_ws, size_t ws_size,
                              hipStream_t stream) {
    const float* x   = (const float*)d_in[0];
    const int*   ei  = (const int*)d_in[1];
    const float* W1  = (const float*)d_in[2];
    const float* a1s = (const float*)d_in[3];
    const float* a1d = (const float*)d_in[4];
    const float* b1  = (const float*)d_in[5];
    const float* W2  = (const float*)d_in[6];
    const float* a2s = (const float*)d_in[7];
    const float* a2d = (const float*)d_in[8];
    const float* b2  = (const float*)d_in[9];
    float* out = (float*)d_out;
    char* base = (char*)d_ws;

    ushort_t* h1b = (ushort_t*)(base + B_H1B);   // head-major [4][10000][512]
    ushort_t* hb  = (ushort_t*)(base + B_HB);    // row-major  [10000][2048]
    ushort_t* xb  = (ushort_t*)(base + B_XB);
    ushort_t* h2b = xb;
    ushort_t* w1t = (ushort_t*)(base + B_W1T);
    ushort_t* w2t = (ushort_t*)(base + B_W2T);
    float*    sm  = (float*)(base + B_SM);

    float* as1  = sm + SM_AS1;
    float* ad1  = sm + SM_AD1;
    float* as2  = sm + SM_AS2;
    float* ad2  = sm + SM_AD2;
    int* cnt    = (int*)(sm + SM_CNT);
    int* rows   = (int*)(sm + SM_ROWS);
    int* curs   = (int*)(sm + SM_CURS);
    int* csr_src = (int*)(base + B_CSRS);
    float* ps1 = (float*)(base + B_PS1);
    float* pd1 = (float*)(base + B_PD1);
    float* ps2 = (float*)(base + B_PS2);
    float* pd2 = (float*)(base + B_PD2);

    // zero the degree histogram only (partials are fully overwritten)
    hipMemsetAsync(cnt, 0, 10000 * sizeof(int), stream);

    // ---------------- casts + CSR build ----------------
    {
        long nx = (long)N_NODES * IN_DIM;
        cast_bf16<<<(int)(nx / 8 / 256 + 1), 256, 0, stream>>>(x, xb, nx);
        cast_transpose<<<dim3(HD1 / 32, IN_DIM / 32), 256, 0, stream>>>(W1, w1t, IN_DIM, HD1);
        cast_transpose<<<dim3(OUT_DIM / 32, HD1 / 32), 256, 0, stream>>>(W2, w2t, HD1, OUT_DIM);
        hist_dst<<<(E_TOTAL + 255) / 256, 256, 0, stream>>>(ei, cnt);
        scan_nodes<<<1, 256, 0, stream>>>(cnt, rows, curs);
        scatter_edges<<<(E_TOTAL + 255) / 256, 256, 0, stream>>>(ei, curs, csr_src);
    }

    // grid geometry: 40 row-blocks, 8 XCDs -> rpx=5 row-panels per XCD
    // gemm1: gx=16 (2048/128), nb=640; gemm2: gx=6 (768/128), nb=240
    // ---------------- layer 1: GATConv(768 -> 512, heads=4, concat) --------
    gemm8p<1><<<640, 512, GEMM_LDS_BYTES, stream>>>(
        xb, w1t, h1b, a1s, a1d, ps1, pd1, N_NODES, HD1, IN_DIM, 16, 5);
    fin1<<<(N_NODES * HEADS + 255) / 256, 256, 0, stream>>>(ps1, pd1, as1, ad1);
    agg1<<<N_NODES * HEADS, 64, 0, stream>>>(
        rows, csr_src, as1, ad1, h1b, b1, hb);

    // ---------------- layer 2: GATConv(2048 -> 768, heads=1, mean) ---------
    gemm8p<0><<<240, 512, GEMM_LDS_BYTES, stream>>>(
        hb, w2t, h2b, a2s, a2d, ps2, pd2, N_NODES, OUT_DIM, HD1, 6, 5);
    fin2<<<(N_NODES + 255) / 256, 256, 0, stream>>>(ps2, pd2, as2, ad2);
    agg2<<<N_NODES / 4, 256, 0, stream>>>(
        rows, csr_src, as2, ad2, h2b, b2, out);
}

// Round 11
// 311.633 us; speedup vs baseline: 1.1615x; 1.0426x over previous
//
#include <hip/hip_runtime.h>
#include <hip/hip_bf16.h>

// ---------------- problem constants ----------------
#define N_NODES 10000
#define E_REAL  80000
#define E_TOTAL 90000
#define IN_DIM  768
#define HID     512
#define HEADS   4
#define OUT_DIM 768
#define HD1     (HEADS * HID)   // 2048
#define NEG_SLOPE 0.2f
#define H1_HSTRIDE (N_NODES * HID)   // head-major h1b: [4][10000][512]

typedef unsigned short ushort_t;
typedef unsigned int uint_t;

// ---------------- bf16 helpers ----------------
__device__ inline float b2f(ushort_t u) { return __uint_as_float(((uint_t)u) << 16); }
__device__ inline ushort_t f2b(float f) {
    __hip_bfloat16 h = __float2bfloat16(f);   // RNE
    return *reinterpret_cast<ushort_t*>(&h);
}

__device__ inline void edge_sd(const int* __restrict__ ei, int e, int& s, int& d) {
    if (e < E_REAL) { s = ei[e]; d = ei[E_REAL + e]; }
    else            { s = e - E_REAL; d = s; }   // self-loop
}

// async global->LDS, 16 B per lane; LDS dest = uniform base + lane*16
#define GLDS(g, l) __builtin_amdgcn_global_load_lds( \
    (const __attribute__((address_space(1))) void*)(g), \
    (__attribute__((address_space(3))) void*)(l), 16, 0, 0)

// ---------------- workspace layout (bytes) ----------------
static const long B_H1B  = 0L;           // h1b bf16 (head-major): 40,960,000
static const long B_HB   = 40960000L;    // hb  bf16 (row-major):  40,960,000
static const long B_XB   = 81920000L;    // xb / h2b bf16: 15,360,000
static const long B_W1T  = 97280000L;    // W1^T bf16
static const long B_W2T  = 100425728L;   // W2^T bf16
static const long B_SM   = 103571456L;
// small-buffer offsets (floats/ints, relative to sm)
static const long SM_AS1   = 0;         // 40000
static const long SM_AD1   = 40000;     // 40000
static const long SM_AS2   = 80000;     // 10000
static const long SM_AD2   = 90000;     // 10000
static const long SM_CNT   = 100000;    // 10000 ints (zeroed each call)
static const long SM_ROWS  = 110000;    // 10001 ints
static const long SM_CURS  = 120016;    // 10000 ints
static const long SM_END   = 130016;
static const long B_CSRS = B_SM + SM_END * 4;   // 90000 ints (src)

// ---------------- fused prep: cast x + transpose W1/W2 + degree hist -----
// Block ranges (all 256 threads):
//   [0, 3750)        : cast x fp32->bf16, 8 elem/thread (exactly 7,680,000)
//   [3750, 5286)     : transpose W1 (768x2048), 32x32 tile t = b-3750,
//                      n0=(t%64)*32, k0=(t/64)*32
//   [5286, 6822)     : transpose W2 (2048x768), t = b-5286,
//                      n0=(t%24)*32, k0=(t/24)*32
//   [6822, 7174)     : degree histogram over E_TOTAL edges
#define PREP_BLOCKS 7174
__global__ __launch_bounds__(256)
void prep(const float* __restrict__ x, ushort_t* __restrict__ xb,
          const float* __restrict__ W1, ushort_t* __restrict__ w1t,
          const float* __restrict__ W2, ushort_t* __restrict__ w2t,
          const int* __restrict__ ei, int* __restrict__ cnt) {
    __shared__ ushort_t t[32][33];
    const int b = blockIdx.x, tid = threadIdx.x;
    if (b < 3750) {
        long i = ((long)b * 256 + tid) * 8;
        float4 v0 = *(const float4*)(x + i);
        float4 v1 = *(const float4*)(x + i + 4);
        ushort_t r[8] = {f2b(v0.x), f2b(v0.y), f2b(v0.z), f2b(v0.w),
                         f2b(v1.x), f2b(v1.y), f2b(v1.z), f2b(v1.w)};
        *(uint4*)(xb + i) = *(uint4*)r;
    } else if (b < 6822) {
        const bool w1 = (b < 5286);
        const int  tt = w1 ? (b - 3750) : (b - 5286);
        const int  K  = w1 ? IN_DIM : HD1;
        const int  N  = w1 ? HD1 : OUT_DIM;
        const int  nb = N / 32;
        const float* W = w1 ? W1 : W2;
        ushort_t* WT   = w1 ? w1t : w2t;
        const int n0 = (tt % nb) * 32, k0 = (tt / nb) * 32;
        const int tx = tid & 31, ty = tid >> 5;
#pragma unroll
        for (int i = 0; i < 4; ++i) {
            int k = ty + i * 8;
            t[k][tx] = f2b(W[(long)(k0 + k) * N + n0 + tx]);
        }
        __syncthreads();
#pragma unroll
        for (int i = 0; i < 4; ++i) {
            int n = ty + i * 8;
            WT[(long)(n0 + n) * K + k0 + tx] = t[tx][n];
        }
    } else {
        int e = (b - 6822) * 256 + tid;
        if (e < E_TOTAL) {
            int s, d; edge_sd(ei, e, s, d);
            atomicAdd(&cnt[d], 1);
        }
    }
}

// ---------------- bf16 MFMA GEMM, 8-phase-style pipelined -----------------
// Tile 256x128, BK=64, 512 threads. Triple-buffered LDS, counted vmcnt(6),
// setprio around MFMA. 1D grid, XCD-chunked swizzle (proven -8.5 us R7):
// XCD k = blockIdx%8 owns bm rows [k*rpx,(k+1)*rpx), bn-major within.
typedef short bf16x8 __attribute__((ext_vector_type(8)));
typedef float f32x4 __attribute__((ext_vector_type(4)));

#define GBM 256
#define GBN 128
#define GBK 64
#define ABUF (GBM * GBK)        // 16384 elements per A buffer
#define BBUF (GBN * GBK)        // 8192 elements per B buffer
#define GEMM_LDS_BYTES ((3 * (ABUF + BBUF)) * 2)   // 147456 B

template<int CMODE>
__global__ __launch_bounds__(512)
void gemm8p(const ushort_t* __restrict__ A, const ushort_t* __restrict__ BT,
            ushort_t* __restrict__ C, int M, int N, int K, int gx, int rpx) {
    extern __shared__ ushort_t sm_[];
    ushort_t* smA = sm_;                 // 3 * ABUF
    ushort_t* smB = sm_ + 3 * ABUF;      // 3 * BBUF
    const int tid  = threadIdx.x;
    const int wave = tid >> 6, lane = tid & 63;
    const int quad = lane >> 4, l16 = lane & 15;
    // XCD-chunked block remap (1D grid)
    const int id  = blockIdx.x;
    const int xcd = id & 7, r = id >> 3;
    const int bm = (xcd * rpx + r / gx) * GBM;
    const int bn = (r % gx) * GBN;
    const int wr = (wave >> 1) * 64, wc = (wave & 1) * 64;
    const int NT = K / GBK;

    const int  rA  = tid >> 3;                                   // 0..63
    const long cs8 = (long)(((tid & 7) ^ ((tid >> 3) & 7)) * 8); // elem offset
    const ushort_t* aSrc = A  + (long)(bm + rA) * K + cs8;
    const ushort_t* bSrc = BT + (long)(bn + rA) * K + cs8;

    const int aRd  = (wr + l16) * GBK;
    const int bRd  = (wc + l16) * GBK;
    const int swz8 = l16 & 7;
    const int chq0 = ((quad)     ^ swz8) * 8;   // kk=0 half
    const int chq1 = ((4 + quad) ^ swz8) * 8;   // kk=1 half

    f32x4 acc[4][4] = {};

    // ---- prologue: stage tiles 0 and 1 ----
#pragma unroll
    for (int tt = 0; tt < 2; ++tt) {
        const long kt = (long)tt * GBK;
#pragma unroll
        for (int i = 0; i < 4; ++i)
            GLDS(aSrc + (long)i * 64 * K + kt,
                 smA + tt * ABUF + (i * 512 + wave * 64) * 8);
#pragma unroll
        for (int i = 0; i < 2; ++i)
            GLDS(bSrc + (long)i * 64 * K + kt,
                 smB + tt * BBUF + (i * 512 + wave * 64) * 8);
    }
    asm volatile("s_waitcnt vmcnt(6)" ::: "memory");   // tile 0 resident
    __builtin_amdgcn_s_barrier();
    __builtin_amdgcn_sched_barrier(0);

    int bc = 0, bnx = 1, bs = 2;   // compute / next / stage buffers
    for (int t = 0; t < NT; ++t) {
        const int offA = bc * ABUF, offB = bc * BBUF;
        const bool stage = (t + 2 < NT);
        const long kt2 = (long)(t + 2) * GBK;
        bf16x8 bfr[2][4], af[2][2];

        // ---------- phase 1: B full + A rows wr..wr+31 ----------
#pragma unroll
        for (int j = 0; j < 4; ++j) {
            bfr[0][j] = *(const bf16x8*)(smB + offB + bRd + j * 1024 + chq0);
            bfr[1][j] = *(const bf16x8*)(smB + offB + bRd + j * 1024 + chq1);
        }
#pragma unroll
        for (int ii = 0; ii < 2; ++ii) {
            af[0][ii] = *(const bf16x8*)(smA + offA + aRd + ii * 1024 + chq0);
            af[1][ii] = *(const bf16x8*)(smA + offA + aRd + ii * 1024 + chq1);
        }
        if (stage) {
            GLDS(aSrc + kt2,                    smA + bs * ABUF + (wave * 64) * 8);
            GLDS(aSrc + (long)1 * 64 * K + kt2, smA + bs * ABUF + (512 + wave * 64) * 8);
            GLDS(aSrc + (long)2 * 64 * K + kt2, smA + bs * ABUF + (1024 + wave * 64) * 8);
        }
        __builtin_amdgcn_sched_barrier(0);
        __builtin_amdgcn_s_barrier();
        __builtin_amdgcn_sched_barrier(0);
        __builtin_amdgcn_s_setprio(1);
#pragma unroll
        for (int kk = 0; kk < 2; ++kk)
#pragma unroll
            for (int ii = 0; ii < 2; ++ii)
#pragma unroll
                for (int j = 0; j < 4; ++j)
                    acc[ii][j] = __builtin_amdgcn_mfma_f32_16x16x32_bf16(
                        af[kk][ii], bfr[kk][j], acc[ii][j], 0, 0, 0);
        __builtin_amdgcn_s_setprio(0);
        __builtin_amdgcn_sched_barrier(0);
        __builtin_amdgcn_s_barrier();
        __builtin_amdgcn_sched_barrier(0);

        // ---------- phase 2: A rows wr+32..wr+63 ----------
#pragma unroll
        for (int ii = 0; ii < 2; ++ii) {
            af[0][ii] = *(const bf16x8*)(smA + offA + aRd + (2 + ii) * 1024 + chq0);
            af[1][ii] = *(const bf16x8*)(smA + offA + aRd + (2 + ii) * 1024 + chq1);
        }
        if (stage) {
            GLDS(aSrc + (long)3 * 64 * K + kt2, smA + bs * ABUF + (1536 + wave * 64) * 8);
            GLDS(bSrc + kt2,                    smB + bs * BBUF + (wave * 64) * 8);
            GLDS(bSrc + (long)1 * 64 * K + kt2, smB + bs * BBUF + (512 + wave * 64) * 8);
        }
        if (stage)             { asm volatile("s_waitcnt vmcnt(6)" ::: "memory"); }
        else if (t + 1 < NT)   { asm volatile("s_waitcnt vmcnt(0)" ::: "memory"); }
        __builtin_amdgcn_sched_barrier(0);
        __builtin_amdgcn_s_barrier();
        __builtin_amdgcn_sched_barrier(0);
        __builtin_amdgcn_s_setprio(1);
#pragma unroll
        for (int kk = 0; kk < 2; ++kk)
#pragma unroll
            for (int ii = 0; ii < 2; ++ii)
#pragma unroll
                for (int j = 0; j < 4; ++j)
                    acc[2 + ii][j] = __builtin_amdgcn_mfma_f32_16x16x32_bf16(
                        af[kk][ii], bfr[kk][j], acc[2 + ii][j], 0, 0, 0);
        __builtin_amdgcn_s_setprio(0);
        __builtin_amdgcn_sched_barrier(0);
        __builtin_amdgcn_s_barrier();
        __builtin_amdgcn_sched_barrier(0);

        int tmp = bc; bc = bnx; bnx = bs; bs = tmp;
    }

    // ---------------- epilogue: C write ----------------
#pragma unroll
    for (int i = 0; i < 4; ++i) {
#pragma unroll
        for (int r2 = 0; r2 < 4; ++r2) {
            int row = bm + wr + i * 16 + quad * 4 + r2;
            if (row >= M) continue;
#pragma unroll
            for (int j = 0; j < 4; ++j) {
                int col = bn + wc + j * 16 + l16;
                if (CMODE == 0) {
                    C[(long)row * N + col] = f2b(acc[i][j][r2]);
                } else {
                    // head-major: head = col>>9
                    C[(long)(col >> 9) * H1_HSTRIDE + (long)row * HID + (col & 511)]
                        = f2b(acc[i][j][r2]);
                }
            }
        }
    }
}

// ---------------- attention dots, layer 1 (head-major h1) ----------------
__global__ __launch_bounds__(256)
void attn1(const ushort_t* __restrict__ h, const float* __restrict__ a_s,
           const float* __restrict__ a_d, float* __restrict__ os,
           float* __restrict__ od) {
    const int n = blockIdx.x;
    const int w = threadIdx.x >> 6, lane = threadIdx.x & 63;
    uint4 hv = *(const uint4*)(h + (long)w * H1_HSTRIDE + (long)n * HID + lane * 8);
    const float* asp = a_s + w * HID + lane * 8;
    const float* adp = a_d + w * HID + lane * 8;
    const ushort_t* pb = (const ushort_t*)&hv;
    float ps = 0.f, pd = 0.f;
#pragma unroll
    for (int c = 0; c < 8; ++c) {
        float v = b2f(pb[c]);
        ps += v * asp[c];
        pd += v * adp[c];
    }
#pragma unroll
    for (int off = 32; off > 0; off >>= 1) {
        ps += __shfl_down(ps, off);
        pd += __shfl_down(pd, off);
    }
    if (lane == 0) { os[n * HEADS + w] = ps; od[n * HEADS + w] = pd; }
}

// ---------------- attention dots, layer 2 (H=1, D=768) -------------------
__global__ __launch_bounds__(256)
void attn2(const ushort_t* __restrict__ h, const float* __restrict__ a_s,
           const float* __restrict__ a_d, float* __restrict__ os,
           float* __restrict__ od) {
    __shared__ float rs[4], rd[4];
    const int n = blockIdx.x, tid = threadIdx.x;
    const int w = tid >> 6, lane = tid & 63;
    float ps = 0.f, pd = 0.f;
#pragma unroll
    for (int j = 0; j < 3; ++j) {
        int c = tid + j * 256;
        float v = b2f(h[(long)n * OUT_DIM + c]);
        ps += v * a_s[c];
        pd += v * a_d[c];
    }
#pragma unroll
    for (int off = 32; off > 0; off >>= 1) {
        ps += __shfl_down(ps, off);
        pd += __shfl_down(pd, off);
    }
    if (lane == 0) { rs[w] = ps; rd[w] = pd; }
    __syncthreads();
    if (tid == 0) {
        os[n] = rs[0] + rs[1] + rs[2] + rs[3];
        od[n] = rd[0] + rd[1] + rd[2] + rd[3];
    }
}

// ---------------- CSR scan + scatter ----------------
#define SCAN_CH 40
__global__ __launch_bounds__(256)
void scan_nodes(const int* __restrict__ cnt, int* __restrict__ rows,
                int* __restrict__ curs) {
    __shared__ int part[256];
    const int tid = threadIdx.x;
    const int base = tid * SCAN_CH;
    int local[SCAN_CH];
    int sum = 0;
#pragma unroll
    for (int i = 0; i < SCAN_CH; ++i) {
        int idx = base + i;
        int v = (idx < N_NODES) ? cnt[idx] : 0;
        local[i] = v; sum += v;
    }
    part[tid] = sum;
    __syncthreads();
    for (int off = 1; off < 256; off <<= 1) {
        int v = (tid >= off) ? part[tid - off] : 0;
        __syncthreads();
        part[tid] += v;
        __syncthreads();
    }
    int run = part[tid] - sum;   // exclusive prefix
#pragma unroll
    for (int i = 0; i < SCAN_CH; ++i) {
        int idx = base + i;
        if (idx < N_NODES) { rows[idx] = run; curs[idx] = run; run += local[i]; }
    }
    if (tid == 255) rows[N_NODES] = run;
}

__global__ __launch_bounds__(256)
void scatter_edges(const int* __restrict__ ei, int* __restrict__ curs,
                   int* __restrict__ csr_src) {
    int e = blockIdx.x * 256 + threadIdx.x;
    if (e >= E_TOTAL) return;
    int s, d; edge_sd(ei, e, s, d);
    int pos = atomicAdd(&curs[d], 1);
    csr_src[pos] = s;
}

// ---------------- layer-1 aggregate + fused softmax + bias + ELU ---------
// R4's measured-best form: one wave per (node, head), 40000 blocks.
// blockIdx%8 maps head h to XCD residues {2h,2h+1} (working-set pinning).
// Per-edge full-wave uint4 gather (1 KB/instr), PF4.
__global__ __launch_bounds__(64)
void agg1(const int* __restrict__ rows, const int* __restrict__ csr_src,
          const float* __restrict__ as_n, const float* __restrict__ ad_n,
          const ushort_t* __restrict__ hf, const float* __restrict__ b1,
          ushort_t* __restrict__ o) {
    const int id = blockIdx.x;
    const int g = id & 7, j = id >> 3;
    const int hh = g >> 1;
    const int n = j * 2 + (g & 1);
    const int lane = threadIdx.x;
    const int beg = rows[n], end = rows[n + 1];
    const ushort_t* hsl = hf + (long)hh * H1_HSTRIDE;
    const float adv = ad_n[(long)n * HEADS + hh];
    float acc[8] = {};
    float dsum = 0.f;
    for (int k = beg; k < end; k += 4) {
        int nk = end - k; if (nk > 4) nk = 4;
        uint4 v[4]; float ex[4];
#pragma unroll
        for (int u = 0; u < 4; ++u) {
            if (u < nk) {
                int s = csr_src[k + u];
                float sc = as_n[(long)s * HEADS + hh] + adv;
                sc = sc > 0.f ? sc : NEG_SLOPE * sc;
                ex[u] = __expf(sc);
                v[u]  = *(const uint4*)(hsl + (long)s * HID + lane * 8);
            }
        }
#pragma unroll
        for (int u = 0; u < 4; ++u) {
            if (u < nk) {
                dsum += ex[u];
                const ushort_t* p = (const ushort_t*)&v[u];
#pragma unroll
                for (int c = 0; c < 8; ++c) acc[c] += ex[u] * b2f(p[c]);
            }
        }
    }
    const float dinv = 1.f / (dsum + 1e-16f);
    const float* bp = b1 + hh * HID + lane * 8;
    ushort_t r[8];
#pragma unroll
    for (int c = 0; c < 8; ++c) {
        float vv = acc[c] * dinv + bp[c];
        r[c] = f2b(vv > 0.f ? vv : expm1f(vv));
    }
    *(uint4*)(o + (long)n * HD1 + hh * HID + lane * 8) = *(uint4*)r;
}

// ---------------- layer-2 aggregate + fused softmax + bias -> fp32 -------
// 4 nodes per 256-thread block (wave = node); unroll depth 8.
#define PF2 8
__global__ __launch_bounds__(256)
void agg2(const int* __restrict__ rows, const int* __restrict__ csr_src,
          const float* __restrict__ as_n, const float* __restrict__ ad_n,
          const ushort_t* __restrict__ hf, const float* __restrict__ b2,
          float* __restrict__ out) {
    const int n = blockIdx.x * 4 + (threadIdx.x >> 6);
    const int lane = threadIdx.x & 63;
    const int beg = rows[n], end = rows[n + 1];
    const float adv = ad_n[n];
    float acc[12] = {};
    float dsum = 0.f;
    for (int k = beg; k < end; k += PF2) {
        int nk = end - k; if (nk > PF2) nk = PF2;
        int sv[PF2];
#pragma unroll
        for (int u = 0; u < PF2; ++u)
            if (u < nk) sv[u] = csr_src[k + u];
        uint4 v4[PF2]; uint2 v2[PF2]; float ex[PF2];
#pragma unroll
        for (int u = 0; u < PF2; ++u) {
            if (u < nk) {
                float sc = as_n[sv[u]] + adv;
                sc = sc > 0.f ? sc : NEG_SLOPE * sc;
                ex[u] = __expf(sc);
                const ushort_t* hp = hf + (long)sv[u] * OUT_DIM;
                v4[u] = *(const uint4*)(hp + lane * 8);
                v2[u] = *(const uint2*)(hp + 512 + lane * 4);
            }
        }
#pragma unroll
        for (int u = 0; u < PF2; ++u) {
            if (u < nk) {
                dsum += ex[u];
                const ushort_t* p4 = (const ushort_t*)&v4[u];
                const ushort_t* p2 = (const ushort_t*)&v2[u];
#pragma unroll
                for (int c = 0; c < 8; ++c) acc[c] += ex[u] * b2f(p4[c]);
#pragma unroll
                for (int c = 0; c < 4; ++c) acc[8 + c] += ex[u] * b2f(p2[c]);
            }
        }
    }
    const float dinv = 1.f / (dsum + 1e-16f);
    float* op = out + (long)n * OUT_DIM;
#pragma unroll
    for (int c = 0; c < 8; ++c)
        op[lane * 8 + c] = acc[c] * dinv + b2[lane * 8 + c];
#pragma unroll
    for (int c = 0; c < 4; ++c)
        op[512 + lane * 4 + c] = acc[8 + c] * dinv + b2[512 + lane * 4 + c];
}

extern "C" void kernel_launch(void* const* d_in, const int* in_sizes, int n_in,
                              void* d_out, int out_size, void* d_ws, size_t ws_size,
                              hipStream_t stream) {
    const float* x   = (const float*)d_in[0];
    const int*   ei  = (const int*)d_in[1];
    const float* W1  = (const float*)d_in[2];
    const float* a1s = (const float*)d_in[3];
    const float* a1d = (const float*)d_in[4];
    const float* b1  = (const float*)d_in[5];
    const float* W2  = (const float*)d_in[6];
    const float* a2s = (const float*)d_in[7];
    const float* a2d = (const float*)d_in[8];
    const float* b2  = (const float*)d_in[9];
    float* out = (float*)d_out;
    char* base = (char*)d_ws;

    ushort_t* h1b = (ushort_t*)(base + B_H1B);   // head-major [4][10000][512]
    ushort_t* hb  = (ushort_t*)(base + B_HB);    // row-major  [10000][2048]
    ushort_t* xb  = (ushort_t*)(base + B_XB);
    ushort_t* h2b = xb;
    ushort_t* w1t = (ushort_t*)(base + B_W1T);
    ushort_t* w2t = (ushort_t*)(base + B_W2T);
    float*    sm  = (float*)(base + B_SM);

    float* as1  = sm + SM_AS1;
    float* ad1  = sm + SM_AD1;
    float* as2  = sm + SM_AS2;
    float* ad2  = sm + SM_AD2;
    int* cnt    = (int*)(sm + SM_CNT);
    int* rows   = (int*)(sm + SM_ROWS);
    int* curs   = (int*)(sm + SM_CURS);
    int* csr_src = (int*)(base + B_CSRS);

    // zero the degree histogram only
    hipMemsetAsync(cnt, 0, 10000 * sizeof(int), stream);

    // ---------------- fused prep (cast + transposes + hist) + CSR ---------
    prep<<<PREP_BLOCKS, 256, 0, stream>>>(x, xb, W1, w1t, W2, w2t, ei, cnt);
    scan_nodes<<<1, 256, 0, stream>>>(cnt, rows, curs);
    scatter_edges<<<(E_TOTAL + 255) / 256, 256, 0, stream>>>(ei, curs, csr_src);

    // grid geometry: 40 row-blocks, 8 XCDs -> rpx=5 row-panels per XCD
    // gemm1: gx=16 (2048/128), nb=640; gemm2: gx=6 (768/128), nb=240
    // ---------------- layer 1: GATConv(768 -> 512, heads=4, concat) --------
    gemm8p<1><<<640, 512, GEMM_LDS_BYTES, stream>>>(
        xb, w1t, h1b, N_NODES, HD1, IN_DIM, 16, 5);
    attn1<<<N_NODES, 256, 0, stream>>>(h1b, a1s, a1d, as1, ad1);
    agg1<<<N_NODES * HEADS, 64, 0, stream>>>(
        rows, csr_src, as1, ad1, h1b, b1, hb);

    // ---------------- layer 2: GATConv(2048 -> 768, heads=1, mean) ---------
    gemm8p<0><<<240, 512, GEMM_LDS_BYTES, stream>>>(
        hb, w2t, h2b, N_NODES, OUT_DIM, HD1, 6, 5);
    attn2<<<N_NODES, 256, 0, stream>>>(h2b, a2s, a2d, as2, ad2);
    agg2<<<N_NODES / 4, 256, 0, stream>>>(
        rows, csr_src, as2, ad2, h2b, b2, out);
}